// Round 8
// baseline (191.119 us; speedup 1.0000x reference)
//
#include <hip/hip_runtime.h>
#include <hip/hip_bf16.h>
#include <math.h>

#define B_DIM 64
#define D_DIM 256
#define C_DIM 100000
#define P_DIM 8
#define N_DIM 32
#define BLK_COLS 128
#define GTILES 782      // ceil(C_DIM / 128) GEMM tiles; block GTILES = h-loss block
#define GRID_TOT (GTILES + 1)
#define NCHUNK 16       // K chunks of 16
#define NBANK 32        // exp-sum accumulator banks

typedef __attribute__((ext_vector_type(8))) short bf16x8;
typedef __attribute__((ext_vector_type(16))) float f32x16;

__device__ __forceinline__ float softplusf(float x) { return log1pf(expf(x)); }

__device__ __forceinline__ short f2bf(float x) {
    __hip_bfloat16 b = __float2bfloat16(x);   // pairs into v_cvt_pk_bf16_f32
    return *reinterpret_cast<short*>(&b);
}

// async 16B global->LDS copy; lds base is wave-uniform (HW adds lane*16)
__device__ __forceinline__ void async_copy16(const float* src, float* lds_base) {
    __builtin_amdgcn_global_load_lds(
        (const __attribute__((address_space(1))) unsigned int*)src,
        (__attribute__((address_space(3))) unsigned int*)lds_base,
        16, 0, 0);
}

// fp32 dot over D=256 with 4 independent accumulation chains
__device__ __forceinline__ float dot256(const float* __restrict__ a, const float* __restrict__ b) {
    float sx = 0.f, sy = 0.f, sz = 0.f, sw = 0.f;
    #pragma unroll 8
    for (int i = 0; i < D_DIM; i += 4) {
        float4 va = *(const float4*)(a + i);
        float4 vb = *(const float4*)(b + i);
        sx += va.x * vb.x; sy += va.y * vb.y;
        sz += va.z * vb.z; sw += va.w * vb.w;
    }
    return (sx + sy) + (sz + sw);
}

// ---------------- Kernel A: X -> bf16 fragment conversion + ws zeroing ----------------
__global__ __launch_bounds__(256)
void frag_kernel(const float* __restrict__ X, unsigned short* __restrict__ wsA,
                 float* __restrict__ wsQ, float* __restrict__ wsT,
                 unsigned int* __restrict__ wsC) {
    const int t = blockIdx.x * 256 + threadIdx.x;   // 0..2047, one fragment each
    const int l = t & 63, kg = (t >> 6) & 15, mt = t >> 10;
    const int row = mt * 32 + (l & 31);
    const int col0 = kg * 16 + 8 * (l >> 5);
    const float* src = X + row * D_DIM + col0;
    float4 v0 = *(const float4*)src;
    float4 v1 = *(const float4*)(src + 4);
    bf16x8 h;
    h[0] = f2bf(v0.x); h[1] = f2bf(v0.y); h[2] = f2bf(v0.z); h[3] = f2bf(v0.w);
    h[4] = f2bf(v1.x); h[5] = f2bf(v1.y); h[6] = f2bf(v1.z); h[7] = f2bf(v1.w);
    *(bf16x8*)(wsA + t * 8) = h;
    if (blockIdx.x == 0) {
        for (int i = threadIdx.x; i < NBANK * 64; i += 256) wsQ[i] = 0.f;
        if (threadIdx.x < 64) wsT[threadIdx.x] = 0.f;
        if (threadIdx.x == 0) wsC[0] = 0u;
    }
}

// ---------------- Kernel B: fused GEMM + exp-sums + h-loss block + final loss ----------------
// Blocks 0..781: 128 V-cols, K in 16 chunks of 16, 3-buffer async-LDS pipeline with
// counted vmcnt. Per-iter VMEM issue order: [A(kc+1) reg-prefetch (2), S(kc+2) (2)];
// entry wait vmcnt(2) => S(kc)+A(kc) done, S(kc+1) still in flight across the barrier.
// Block 782: h-loss (on-demand fp32 dots for the 2560 needed sim entries).
// Last finishing block computes the final scalar loss.
__global__ __launch_bounds__(256)
void logits_kernel(const float* __restrict__ V, const float* __restrict__ X,
                   const unsigned short* __restrict__ wsA,
                   const int* __restrict__ targets,
                   const int* __restrict__ pos_idx, const int* __restrict__ pos_mask,
                   const int* __restrict__ neg_idx, const int* __restrict__ neg_mask,
                   float* __restrict__ out,
                   float* __restrict__ wsQ, float* __restrict__ wsT,
                   float* __restrict__ wsH, unsigned int* __restrict__ wsC) {
    __shared__ float shm[8704];                // stage 3*2048 = 24 KB; epilogue 34 KB
    const int tid = threadIdx.x;
    const int w = tid >> 6, l = tid & 63;
    const int hi = l >> 5;

    if (blockIdx.x < GTILES) {
        // ================= GEMM path =================
        const int c0 = blockIdx.x * BLK_COLS;

        // stage chunk kc (128 cols x 16 k = 8 KB) into buffer b; 16B units XOR-swizzled
        // with unit ^= (col>>1)&3 (applied on the GLOBAL source; gload_lds dest linear).
        #define STAGE(kc, b)                                                        \
            {                                                                       \
                _Pragma("unroll")                                                   \
                for (int j = 0; j < 2; ++j) {                                       \
                    int U = (j * 4 + w) * 64 + l;                                   \
                    int colL = U >> 2, up = U & 3;                                  \
                    int us = up ^ ((colL >> 1) & 3);                                \
                    int cc = c0 + colL; cc = (cc < C_DIM) ? cc : (C_DIM - 1);       \
                    const float* src = V + (size_t)cc * D_DIM + (kc) * 16 + us * 4; \
                    async_copy16(src, &shm[(b) * 2048 + (j * 4 + w) * 256]);        \
                }                                                                   \
            }
        #define AFETCH(kc, s)                                                       \
            {                                                                       \
                frg[s][0] = *(const bf16x8*)(wsA + (((kc)     ) * 64 + l) * 8);     \
                frg[s][1] = *(const bf16x8*)(wsA + (((kc) + 16) * 64 + l) * 8);     \
            }

        bf16x8 frg[2][2];
        AFETCH(0, 0);
        STAGE(0, 0);
        STAGE(1, 1);

        f32x16 acc0, acc1;                     // batch rows 0-31, 32-63
        #pragma unroll
        for (int i = 0; i < 16; ++i) { acc0[i] = 0.0f; acc1[i] = 0.0f; }

        const int colL = w * 32 + (l & 31);
        const int cbase = colL * 16;
        const int cm = (colL >> 1) & 3;

        #pragma unroll
        for (int kc = 0; kc < NCHUNK; ++kc) {
            if (kc < NCHUNK - 1) asm volatile("s_waitcnt vmcnt(2)" ::: "memory");
            else                 asm volatile("s_waitcnt vmcnt(0)" ::: "memory");
            __builtin_amdgcn_s_barrier();      // all waves' S(kc) landed
            asm volatile("" ::: "memory");
            __builtin_amdgcn_sched_barrier(0);
            if (kc < NCHUNK - 1) AFETCH(kc + 1, (kc + 1) & 1);
            if (kc < NCHUNK - 2) STAGE(kc + 2, (kc + 2) % 3);   // buf (kc-1)%3: free since barrier
            const float* vb = &shm[(kc % 3) * 2048];
            const int u0 = 2 * hi;
            float4 v0 = *(const float4*)&vb[cbase + ((u0    ) ^ cm) * 4];
            float4 v1 = *(const float4*)&vb[cbase + ((u0 + 1) ^ cm) * 4];
            bf16x8 vh;
            vh[0] = f2bf(v0.x); vh[1] = f2bf(v0.y); vh[2] = f2bf(v0.z); vh[3] = f2bf(v0.w);
            vh[4] = f2bf(v1.x); vh[5] = f2bf(v1.y); vh[6] = f2bf(v1.z); vh[7] = f2bf(v1.w);
            const bf16x8 a0 = frg[kc & 1][0], a1 = frg[kc & 1][1];
            acc0 = __builtin_amdgcn_mfma_f32_32x32x16_bf16(vh, a0, acc0, 0, 0, 0);
            acc1 = __builtin_amdgcn_mfma_f32_32x32x16_bf16(vh, a1, acc1, 0, 0, 0);
        }
        #undef STAGE
        #undef AFETCH
        __syncthreads();                       // compute done; shm free for epilogue

        // ---- epilogue: lane-local exp-sums + target capture + LDS transpose ----
        float* ldsT = &shm[w * 2112];          // [64 b][33 c] per wave
        float* sred = &shm[8448];              // [4 waves][64 b]
        const int b0 = l & 31, b1 = 32 + (l & 31);
        const int tb0 = targets[b0], tb1 = targets[b1];
        float s0 = 0.0f, s1 = 0.0f;
        #pragma unroll
        for (int r = 0; r < 16; ++r) {
            const int cl = (r & 3) + 8 * (r >> 2) + 4 * hi;
            const int c = c0 + w * 32 + cl;
            const float v0 = acc0[r], v1 = acc1[r];
            ldsT[b0 * 33 + cl] = v0;
            ldsT[b1 * 33 + cl] = v1;
            if (c < C_DIM) {
                s0 += expf(v0);
                s1 += expf(v1);
                if (c == tb0) atomicAdd(&wsT[b0], v0);
                if (c == tb1) atomicAdd(&wsT[b1], v1);
            }
        }
        s0 += __shfl_xor(s0, 32);              // add the partner c-half
        s1 += __shfl_xor(s1, 32);
        if (l < 32) { sred[w * 64 + l] = s0; sred[w * 64 + 32 + l] = s1; }
        __syncthreads();
        if (tid < 64) {
            float s = (sred[tid] + sred[64 + tid]) + (sred[128 + tid] + sred[192 + tid]);
            atomicAdd(&wsQ[(blockIdx.x & (NBANK - 1)) * 64 + tid], s);
        }
        const int cg = c0 + w * 32 + (l & 31);
        if (cg < C_DIM) {
            #pragma unroll
            for (int rr = 0; rr < 32; ++rr) {
                const int b = 2 * rr + hi;
                out[1 + (size_t)b * C_DIM + cg] = ldsT[b * 33 + (l & 31)];
            }
        }
    } else {
        // ================= h-loss block =================
        float* inv = shm;                      // [64]
        float* contrib = shm + 64;             // [64]
        const int r = tid >> 2, q = tid & 3;
        {
            const float* row = X + r * D_DIM + q * 64;
            float s = 0.0f;
            #pragma unroll
            for (int i = 0; i < 64; i += 4) {
                float4 v = *(const float4*)(row + i);
                s += v.x * v.x + v.y * v.y + v.z * v.z + v.w * v.w;
            }
            s += __shfl_xor(s, 1);
            s += __shfl_xor(s, 2);
            if (q == 0) inv[r] = 1.0f / fmaxf(sqrtf(s), 1e-12f);
        }
        __syncthreads();
        const float* Ar = X + r * D_DIM;
        const float ir = inv[r];
        const float INF = __int_as_float(0x7f800000);
        float m = INF;
        #pragma unroll
        for (int pp = 0; pp < 2; ++pp) {
            int p = q * 2 + pp;
            if (pos_mask[r * P_DIM + p]) {
                int j = pos_idx[r * P_DIM + p];
                float d = dot256(Ar, X + j * D_DIM) * ir * inv[j];
                m = fminf(m, d);
            }
        }
        m = fminf(m, __shfl_xor(m, 1));
        m = fminf(m, __shfl_xor(m, 2));
        const float thr = m - 0.3f;
        float sum = 0.0f; int cnt = 0;
        #pragma unroll 2
        for (int nn = 0; nn < 8; ++nn) {
            int n = q * 8 + nn;
            if (neg_mask[r * N_DIM + n]) {
                int j = neg_idx[r * N_DIM + n];
                float d = dot256(Ar, X + j * D_DIM) * ir * inv[j];
                if (d > thr) { cnt += 1; sum += softplusf(d); }
            }
        }
        sum += __shfl_xor(sum, 1); cnt += __shfl_xor(cnt, 1);
        sum += __shfl_xor(sum, 2); cnt += __shfl_xor(cnt, 2);
        if (q == 0) contrib[r] = softplusf(-m) + ((cnt > 0) ? sum / (float)cnt : 0.0f);
        __syncthreads();
        if (tid == 0) {
            float s = 0.0f;
            for (int i = 0; i < 64; ++i) s += contrib[i];
            wsH[0] = s * (1.0f / 64.0f);
        }
    }

    // ================= last-block-done: final loss =================
    __syncthreads();
    __threadfence();
    if (tid == 0) {
        unsigned int old = atomicAdd(wsC, 1u);
        ((int*)shm)[0] = (old == (unsigned int)(GRID_TOT - 1)) ? 1 : 0;
    }
    __syncthreads();
    if (((int*)shm)[0] && tid < 64) {
        float S = 0.0f;
        #pragma unroll
        for (int k = 0; k < NBANK; ++k) S += atomicAdd(&wsQ[k * 64 + tid], 0.0f);
        float T = atomicAdd(&wsT[tid], 0.0f);
        float lb = logf(S) - T;
        #pragma unroll
        for (int m = 1; m <= 32; m <<= 1) lb += __shfl_xor(lb, m);
        if (tid == 0) out[0] = lb * (1.0f / 64.0f) + atomicAdd(&wsH[0], 0.0f);
    }
}

extern "C" void kernel_launch(void* const* d_in, const int* in_sizes, int n_in,
                              void* d_out, int out_size, void* d_ws, size_t ws_size,
                              hipStream_t stream) {
    (void)in_sizes; (void)n_in; (void)out_size; (void)ws_size;
    const float* X        = (const float*)d_in[0];
    const float* V        = (const float*)d_in[1];
    const int*   targets  = (const int*)d_in[2];
    const int*   pos_idx  = (const int*)d_in[3];
    const int*   pos_mask = (const int*)d_in[4];
    const int*   neg_idx  = (const int*)d_in[5];
    const int*   neg_mask = (const int*)d_in[6];
    float* out = (float*)d_out;
    float*          wsH = (float*)d_ws;                              // 64 floats
    float*          wsQ = (float*)d_ws + 64;                         // NBANK*64 = 2048
    float*          wsT = (float*)d_ws + 64 + NBANK * 64;            // 64
    unsigned int*   wsC = (unsigned int*)((float*)d_ws + 64 + NBANK * 64 + 64);
    unsigned short* wsA = (unsigned short*)((char*)d_ws + 32768);    // 32 KB A-fragments

    hipLaunchKernelGGL(frag_kernel, dim3(8), dim3(256), 0, stream, X, wsA, wsQ, wsT, wsC);
    hipLaunchKernelGGL(logits_kernel, dim3(GRID_TOT), dim3(256), 0, stream,
                       V, X, wsA, targets, pos_idx, pos_mask, neg_idx, neg_mask,
                       out, wsQ, wsT, wsH, wsC);
}

// Round 9
// 180.077 us; speedup vs baseline: 1.0613x; 1.0613x over previous
//
#include <hip/hip_runtime.h>
#include <hip/hip_bf16.h>
#include <math.h>

#define B_DIM 64
#define D_DIM 256
#define C_DIM 100000
#define P_DIM 8
#define N_DIM 32
#define BLK_COLS 128
#define GTILES 782      // ceil(C_DIM / 128) GEMM tiles; block GTILES = h-loss block
#define GRID_TOT (GTILES + 1)
#define NCHUNK 8        // K chunks of 32
#define NBANK 64        // exp-sum accumulator banks

typedef __attribute__((ext_vector_type(8))) short bf16x8;
typedef __attribute__((ext_vector_type(16))) float f32x16;

__device__ __forceinline__ float softplusf(float x) { return log1pf(expf(x)); }

__device__ __forceinline__ short f2bf(float x) {
    __hip_bfloat16 b = __float2bfloat16(x);   // pairs into v_cvt_pk_bf16_f32
    return *reinterpret_cast<short*>(&b);
}

// async 16B global->LDS copy; lds base is wave-uniform (HW adds lane*16)
__device__ __forceinline__ void async_copy16(const float* src, float* lds_base) {
    __builtin_amdgcn_global_load_lds(
        (const __attribute__((address_space(1))) unsigned int*)src,
        (__attribute__((address_space(3))) unsigned int*)lds_base,
        16, 0, 0);
}

// fp32 dot over D=256 with 4 independent accumulation chains
__device__ __forceinline__ float dot256(const float* __restrict__ a, const float* __restrict__ b) {
    float sx = 0.f, sy = 0.f, sz = 0.f, sw = 0.f;
    #pragma unroll 8
    for (int i = 0; i < D_DIM; i += 4) {
        float4 va = *(const float4*)(a + i);
        float4 vb = *(const float4*)(b + i);
        sx += va.x * vb.x; sy += va.y * vb.y;
        sz += va.z * vb.z; sw += va.w * vb.w;
    }
    return (sx + sy) + (sz + sw);
}

// ---------------- Kernel A: X -> bf16 fragment conversion + ws zeroing ----------------
__global__ __launch_bounds__(256)
void frag_kernel(const float* __restrict__ X, unsigned short* __restrict__ wsA,
                 float* __restrict__ wsQ, float* __restrict__ wsT,
                 unsigned int* __restrict__ wsC) {
    const int t = blockIdx.x * 256 + threadIdx.x;   // 0..2047, one fragment each
    const int l = t & 63, kg = (t >> 6) & 15, mt = t >> 10;
    const int row = mt * 32 + (l & 31);
    const int col0 = kg * 16 + 8 * (l >> 5);
    const float* src = X + row * D_DIM + col0;
    float4 v0 = *(const float4*)src;
    float4 v1 = *(const float4*)(src + 4);
    bf16x8 h;
    h[0] = f2bf(v0.x); h[1] = f2bf(v0.y); h[2] = f2bf(v0.z); h[3] = f2bf(v0.w);
    h[4] = f2bf(v1.x); h[5] = f2bf(v1.y); h[6] = f2bf(v1.z); h[7] = f2bf(v1.w);
    *(bf16x8*)(wsA + t * 8) = h;
    if (blockIdx.x == 0) {
        for (int i = threadIdx.x; i < NBANK * 64; i += 256) wsQ[i] = 0.f;
        if (threadIdx.x < 64) wsT[threadIdx.x] = 0.f;
        if (threadIdx.x == 0) wsC[0] = 0u;
    }
}

// ---------------- Kernel B: fused GEMM + exp-sums + h-loss block + final loss ----------------
// Blocks 0..781 (R6-proven loop): 128 V-cols, K in 8 chunks of 32, double-buffered
// async-LDS staging, plain __syncthreads per chunk (compiler-managed waits; implicit
// cross-block overlap at 4 blocks/CU covers the barrier drain — m114).
// Block 782: h-loss via on-demand fp32 dots (2560 sim entries, not the full 64x64).
// Last finishing block computes the final scalar loss (device-scope RMW reads).
__global__ __launch_bounds__(256)
void logits_kernel(const float* __restrict__ V, const float* __restrict__ X,
                   const unsigned short* __restrict__ wsA,
                   const int* __restrict__ targets,
                   const int* __restrict__ pos_idx, const int* __restrict__ pos_mask,
                   const int* __restrict__ neg_idx, const int* __restrict__ neg_mask,
                   float* __restrict__ out,
                   float* __restrict__ wsQ, float* __restrict__ wsT,
                   float* __restrict__ wsH, unsigned int* __restrict__ wsC) {
    __shared__ float shm[8768];                // stage 2x16 KB; epilogue reuses 34 KB
    const int tid = threadIdx.x;
    const int w = tid >> 6, l = tid & 63;
    const int hi = l >> 5;

    if (blockIdx.x < GTILES) {
        // ================= GEMM path (R6 structure) =================
        const int c0 = blockIdx.x * BLK_COLS;

        // stage chunk kc (128 cols x 32 k = 16 KB) into buffer b; 16B units XOR-swizzled
        // (unit ^= col&7) applied on the GLOBAL source; gload_lds dest stays linear.
        #define STAGE(kc, b)                                                        \
            {                                                                       \
                _Pragma("unroll")                                                   \
                for (int j = 0; j < 4; ++j) {                                       \
                    int U = (j * 4 + w) * 64 + l;                                   \
                    int colL = U >> 3, up = U & 7;                                  \
                    int us = up ^ (colL & 7);                                       \
                    int cc = c0 + colL; cc = (cc < C_DIM) ? cc : (C_DIM - 1);       \
                    const float* src = V + (size_t)cc * D_DIM + (kc) * 32 + us * 4; \
                    async_copy16(src, &shm[(b) * 4096 + (j * 4 + w) * 256]);        \
                }                                                                   \
            }

        STAGE(0, 0);
        __syncthreads();

        f32x16 acc0, acc1;                     // batch rows 0-31, 32-63
        #pragma unroll
        for (int i = 0; i < 16; ++i) { acc0[i] = 0.0f; acc1[i] = 0.0f; }

        const int colL = w * 32 + (l & 31);
        const int cbase = colL * 32;           // 8 units * 4 floats per col
        const int cm7 = colL & 7;

        for (int kc = 0; kc < NCHUNK; ++kc) {
            if (kc < NCHUNK - 1) STAGE(kc + 1, (kc + 1) & 1);
            const float* vb = &shm[(kc & 1) * 4096];
            #pragma unroll
            for (int h = 0; h < 2; ++h) {
                const int kg = kc * 2 + h;
                const bf16x8 a0 = *(const bf16x8*)(wsA + ((0 * 16 + kg) * 64 + l) * 8);
                const bf16x8 a1 = *(const bf16x8*)(wsA + ((1 * 16 + kg) * 64 + l) * 8);
                const int u0 = h * 4 + 2 * hi;
                float4 v0 = *(const float4*)&vb[cbase + ((u0    ) ^ cm7) * 4];
                float4 v1 = *(const float4*)&vb[cbase + ((u0 + 1) ^ cm7) * 4];
                bf16x8 vh;
                vh[0] = f2bf(v0.x); vh[1] = f2bf(v0.y); vh[2] = f2bf(v0.z); vh[3] = f2bf(v0.w);
                vh[4] = f2bf(v1.x); vh[5] = f2bf(v1.y); vh[6] = f2bf(v1.z); vh[7] = f2bf(v1.w);
                // TRANSPOSED: A = V fragment, B = X fragment
                acc0 = __builtin_amdgcn_mfma_f32_32x32x16_bf16(vh, a0, acc0, 0, 0, 0);
                acc1 = __builtin_amdgcn_mfma_f32_32x32x16_bf16(vh, a1, acc1, 0, 0, 0);
            }
            __syncthreads();
        }
        #undef STAGE

        // ---- epilogue: lane-local exp-sums + target capture + LDS transpose ----
        float* ldsT = &shm[w * 2112];          // [64 b][33 c] per wave
        float* sred = &shm[8448];              // [4 waves][64 b]
        const int b0 = l & 31, b1 = 32 + (l & 31);
        const int tb0 = targets[b0], tb1 = targets[b1];
        float s0 = 0.0f, s1 = 0.0f;
        #pragma unroll
        for (int r = 0; r < 16; ++r) {
            const int cl = (r & 3) + 8 * (r >> 2) + 4 * hi;
            const int c = c0 + w * 32 + cl;
            const float v0 = acc0[r], v1 = acc1[r];
            ldsT[b0 * 33 + cl] = v0;
            ldsT[b1 * 33 + cl] = v1;
            if (c < C_DIM) {
                s0 += expf(v0);
                s1 += expf(v1);
                if (c == tb0) atomicAdd(&wsT[b0], v0);
                if (c == tb1) atomicAdd(&wsT[b1], v1);
            }
        }
        s0 += __shfl_xor(s0, 32);              // add the partner c-half
        s1 += __shfl_xor(s1, 32);
        if (l < 32) { sred[w * 64 + l] = s0; sred[w * 64 + 32 + l] = s1; }
        __syncthreads();
        if (tid < 64) {
            float s = (sred[tid] + sred[64 + tid]) + (sred[128 + tid] + sred[192 + tid]);
            atomicAdd(&wsQ[(blockIdx.x & (NBANK - 1)) * 64 + tid], s);
        }
        const int cg = c0 + w * 32 + (l & 31);
        if (cg < C_DIM) {
            #pragma unroll
            for (int rr = 0; rr < 32; ++rr) {
                const int b = 2 * rr + hi;
                out[1 + (size_t)b * C_DIM + cg] = ldsT[b * 33 + (l & 31)];
            }
        }
    } else {
        // ================= h-loss block =================
        float* inv = shm;                      // [64]
        float* contrib = shm + 64;             // [64]
        const int r = tid >> 2, q = tid & 3;
        {
            const float* row = X + r * D_DIM + q * 64;
            float s = 0.0f;
            #pragma unroll
            for (int i = 0; i < 64; i += 4) {
                float4 v = *(const float4*)(row + i);
                s += v.x * v.x + v.y * v.y + v.z * v.z + v.w * v.w;
            }
            s += __shfl_xor(s, 1);
            s += __shfl_xor(s, 2);
            if (q == 0) inv[r] = 1.0f / fmaxf(sqrtf(s), 1e-12f);
        }
        __syncthreads();
        const float* Ar = X + r * D_DIM;
        const float ir = inv[r];
        const float INF = __int_as_float(0x7f800000);
        float m = INF;
        #pragma unroll
        for (int pp = 0; pp < 2; ++pp) {
            int p = q * 2 + pp;
            if (pos_mask[r * P_DIM + p]) {
                int j = pos_idx[r * P_DIM + p];
                float d = dot256(Ar, X + j * D_DIM) * ir * inv[j];
                m = fminf(m, d);
            }
        }
        m = fminf(m, __shfl_xor(m, 1));
        m = fminf(m, __shfl_xor(m, 2));
        const float thr = m - 0.3f;
        float sum = 0.0f; int cnt = 0;
        #pragma unroll 2
        for (int nn = 0; nn < 8; ++nn) {
            int n = q * 8 + nn;
            if (neg_mask[r * N_DIM + n]) {
                int j = neg_idx[r * N_DIM + n];
                float d = dot256(Ar, X + j * D_DIM) * ir * inv[j];
                if (d > thr) { cnt += 1; sum += softplusf(d); }
            }
        }
        sum += __shfl_xor(sum, 1); cnt += __shfl_xor(cnt, 1);
        sum += __shfl_xor(sum, 2); cnt += __shfl_xor(cnt, 2);
        if (q == 0) contrib[r] = softplusf(-m) + ((cnt > 0) ? sum / (float)cnt : 0.0f);
        __syncthreads();
        if (tid == 0) {
            float s = 0.0f;
            for (int i = 0; i < 64; ++i) s += contrib[i];
            wsH[0] = s * (1.0f / 64.0f);
        }
    }

    // ================= last-block-done: final loss =================
    __syncthreads();
    __threadfence();
    if (tid == 0) {
        unsigned int old = atomicAdd(wsC, 1u);
        ((int*)shm)[0] = (old == (unsigned int)(GRID_TOT - 1)) ? 1 : 0;
    }
    __syncthreads();
    if (((int*)shm)[0] && tid < 64) {
        float S = 0.0f;
        #pragma unroll
        for (int k = 0; k < NBANK; ++k) S += atomicAdd(&wsQ[k * 64 + tid], 0.0f);
        float T = atomicAdd(&wsT[tid], 0.0f);
        float lb = logf(S) - T;
        #pragma unroll
        for (int m = 1; m <= 32; m <<= 1) lb += __shfl_xor(lb, m);
        if (tid == 0) out[0] = lb * (1.0f / 64.0f) + atomicAdd(&wsH[0], 0.0f);
    }
}

extern "C" void kernel_launch(void* const* d_in, const int* in_sizes, int n_in,
                              void* d_out, int out_size, void* d_ws, size_t ws_size,
                              hipStream_t stream) {
    (void)in_sizes; (void)n_in; (void)out_size; (void)ws_size;
    const float* X        = (const float*)d_in[0];
    const float* V        = (const float*)d_in[1];
    const int*   targets  = (const int*)d_in[2];
    const int*   pos_idx  = (const int*)d_in[3];
    const int*   pos_mask = (const int*)d_in[4];
    const int*   neg_idx  = (const int*)d_in[5];
    const int*   neg_mask = (const int*)d_in[6];
    float* out = (float*)d_out;
    float*          wsH = (float*)d_ws;                              // 64 floats
    float*          wsQ = (float*)d_ws + 64;                         // NBANK*64 = 4096
    float*          wsT = (float*)d_ws + 64 + NBANK * 64;            // 64
    unsigned int*   wsC = (unsigned int*)((float*)d_ws + 64 + NBANK * 64 + 64);
    unsigned short* wsA = (unsigned short*)((char*)d_ws + 32768);    // 32 KB A-fragments

    hipLaunchKernelGGL(frag_kernel, dim3(8), dim3(256), 0, stream, X, wsA, wsQ, wsT, wsC);
    hipLaunchKernelGGL(logits_kernel, dim3(GRID_TOT), dim3(256), 0, stream,
                       V, X, wsA, targets, pos_idx, pos_mask, neg_idx, neg_mask,
                       out, wsQ, wsT, wsH, wsC);
}

// Round 10
// 88.502 us; speedup vs baseline: 2.1595x; 2.0347x over previous
//
#include <hip/hip_runtime.h>
#include <hip/hip_bf16.h>
#include <math.h>

#define B_DIM 64
#define D_DIM 256
#define C_DIM 100000
#define P_DIM 8
#define N_DIM 32
#define BLK_COLS 128
#define GTILES 782      // ceil(C_DIM / 128) GEMM tiles; block GTILES = h-loss block
#define GRID_TOT (GTILES + 1)
#define NCHUNK 8        // K chunks of 32
#define NBANK 64        // exp-sum accumulator banks

typedef __attribute__((ext_vector_type(8))) short bf16x8;
typedef __attribute__((ext_vector_type(16))) float f32x16;

__device__ __forceinline__ float softplusf(float x) { return log1pf(expf(x)); }

__device__ __forceinline__ short f2bf(float x) {
    __hip_bfloat16 b = __float2bfloat16(x);   // pairs into v_cvt_pk_bf16_f32
    return *reinterpret_cast<short*>(&b);
}

// async 16B global->LDS copy; lds base is wave-uniform (HW adds lane*16)
__device__ __forceinline__ void async_copy16(const float* src, float* lds_base) {
    __builtin_amdgcn_global_load_lds(
        (const __attribute__((address_space(1))) unsigned int*)src,
        (__attribute__((address_space(3))) unsigned int*)lds_base,
        16, 0, 0);
}

// fp32 dot over D=256 with 4 independent accumulation chains
__device__ __forceinline__ float dot256(const float* __restrict__ a, const float* __restrict__ b) {
    float sx = 0.f, sy = 0.f, sz = 0.f, sw = 0.f;
    #pragma unroll 8
    for (int i = 0; i < D_DIM; i += 4) {
        float4 va = *(const float4*)(a + i);
        float4 vb = *(const float4*)(b + i);
        sx += va.x * vb.x; sy += va.y * vb.y;
        sz += va.z * vb.z; sw += va.w * vb.w;
    }
    return (sx + sy) + (sz + sw);
}

// ---------------- Kernel A: X -> bf16 fragment conversion + ws zeroing ----------------
__global__ __launch_bounds__(256)
void frag_kernel(const float* __restrict__ X, unsigned short* __restrict__ wsA,
                 float* __restrict__ wsQ, float* __restrict__ wsT) {
    const int t = blockIdx.x * 256 + threadIdx.x;   // 0..2047, one fragment each
    const int l = t & 63, kg = (t >> 6) & 15, mt = t >> 10;
    const int row = mt * 32 + (l & 31);
    const int col0 = kg * 16 + 8 * (l >> 5);
    const float* src = X + row * D_DIM + col0;
    float4 v0 = *(const float4*)src;
    float4 v1 = *(const float4*)(src + 4);
    bf16x8 h;
    h[0] = f2bf(v0.x); h[1] = f2bf(v0.y); h[2] = f2bf(v0.z); h[3] = f2bf(v0.w);
    h[4] = f2bf(v1.x); h[5] = f2bf(v1.y); h[6] = f2bf(v1.z); h[7] = f2bf(v1.w);
    *(bf16x8*)(wsA + t * 8) = h;
    if (blockIdx.x == 0) {
        for (int i = threadIdx.x; i < NBANK * 64; i += 256) wsQ[i] = 0.f;
        if (threadIdx.x < 64) wsT[threadIdx.x] = 0.f;
    }
}

// ---------------- Kernel B: logits GEMM (R6 structure) + exp-sums + h-loss block ----------------
// Blocks 0..781: 128 V-cols, K in 8 chunks of 32, double-buffered async-LDS staging,
// plain __syncthreads per chunk (compiler-managed waits; implicit cross-block overlap
// at ~4 blocks/CU covers the barrier drain — m114). Block 782: h-loss via on-demand
// fp32 dots (2560 sim entries). NO device fences / last-block pattern (R5/R8/R9 lesson:
// per-block __threadfence costs ~3x the whole kernel on gfx950).
__global__ __launch_bounds__(256)
void logits_kernel(const float* __restrict__ V, const float* __restrict__ X,
                   const unsigned short* __restrict__ wsA,
                   const int* __restrict__ targets,
                   const int* __restrict__ pos_idx, const int* __restrict__ pos_mask,
                   const int* __restrict__ neg_idx, const int* __restrict__ neg_mask,
                   float* __restrict__ out,
                   float* __restrict__ wsQ, float* __restrict__ wsT,
                   float* __restrict__ wsH) {
    __shared__ float shm[8768];                // stage 2x16 KB; epilogue reuses 34 KB
    __shared__ int tgt[64];
    const int tid = threadIdx.x;
    const int w = tid >> 6, l = tid & 63;
    const int hi = l >> 5;

    if (blockIdx.x < GTILES) {
        // ================= GEMM path (R6 verbatim) =================
        const int c0 = blockIdx.x * BLK_COLS;
        if (tid < 64) tgt[tid] = targets[tid];

        // stage chunk kc (128 cols x 32 k = 16 KB) into buffer b; 16B units XOR-swizzled
        // (unit ^= col&7) applied on the GLOBAL source; gload_lds dest stays linear.
        #define STAGE(kc, b)                                                        \
            {                                                                       \
                _Pragma("unroll")                                                   \
                for (int j = 0; j < 4; ++j) {                                       \
                    int U = (j * 4 + w) * 64 + l;                                   \
                    int colL = U >> 3, up = U & 7;                                  \
                    int us = up ^ (colL & 7);                                       \
                    int cc = c0 + colL; cc = (cc < C_DIM) ? cc : (C_DIM - 1);       \
                    const float* src = V + (size_t)cc * D_DIM + (kc) * 32 + us * 4; \
                    async_copy16(src, &shm[(b) * 4096 + (j * 4 + w) * 256]);        \
                }                                                                   \
            }

        STAGE(0, 0);
        __syncthreads();

        f32x16 acc0, acc1;                     // batch rows 0-31, 32-63
        #pragma unroll
        for (int i = 0; i < 16; ++i) { acc0[i] = 0.0f; acc1[i] = 0.0f; }

        const int colL = w * 32 + (l & 31);
        const int cbase = colL * 32;           // 8 units * 4 floats per col
        const int cm7 = colL & 7;

        for (int kc = 0; kc < NCHUNK; ++kc) {
            if (kc < NCHUNK - 1) STAGE(kc + 1, (kc + 1) & 1);
            const float* vb = &shm[(kc & 1) * 4096];
            #pragma unroll
            for (int h = 0; h < 2; ++h) {
                const int kg = kc * 2 + h;
                const bf16x8 a0 = *(const bf16x8*)(wsA + ((0 * 16 + kg) * 64 + l) * 8);
                const bf16x8 a1 = *(const bf16x8*)(wsA + ((1 * 16 + kg) * 64 + l) * 8);
                const int u0 = h * 4 + 2 * hi;
                float4 v0 = *(const float4*)&vb[cbase + ((u0    ) ^ cm7) * 4];
                float4 v1 = *(const float4*)&vb[cbase + ((u0 + 1) ^ cm7) * 4];
                bf16x8 vh;
                vh[0] = f2bf(v0.x); vh[1] = f2bf(v0.y); vh[2] = f2bf(v0.z); vh[3] = f2bf(v0.w);
                vh[4] = f2bf(v1.x); vh[5] = f2bf(v1.y); vh[6] = f2bf(v1.z); vh[7] = f2bf(v1.w);
                // TRANSPOSED: A = V fragment, B = X fragment
                acc0 = __builtin_amdgcn_mfma_f32_32x32x16_bf16(vh, a0, acc0, 0, 0, 0);
                acc1 = __builtin_amdgcn_mfma_f32_32x32x16_bf16(vh, a1, acc1, 0, 0, 0);
            }
            __syncthreads();
        }
        #undef STAGE

        // ---- epilogue: lane-local exp-sums + target capture + LDS transpose ----
        float* ldsT = &shm[w * 2112];          // [64 b][33 c] per wave
        float* sred = &shm[8448];              // [4 waves][64 b]
        const int b0 = l & 31, b1 = 32 + (l & 31);
        const int tb0 = tgt[b0], tb1 = tgt[b1];
        float s0 = 0.0f, s1 = 0.0f;
        #pragma unroll
        for (int r = 0; r < 16; ++r) {
            const int cl = (r & 3) + 8 * (r >> 2) + 4 * hi;
            const int c = c0 + w * 32 + cl;
            const float v0 = acc0[r], v1 = acc1[r];
            ldsT[b0 * 33 + cl] = v0;
            ldsT[b1 * 33 + cl] = v1;
            if (c < C_DIM) {
                s0 += expf(v0);
                s1 += expf(v1);
                if (c == tb0) atomicAdd(&wsT[b0], v0);
                if (c == tb1) atomicAdd(&wsT[b1], v1);
            }
        }
        s0 += __shfl_xor(s0, 32);              // add the partner c-half
        s1 += __shfl_xor(s1, 32);
        if (l < 32) { sred[w * 64 + l] = s0; sred[w * 64 + 32 + l] = s1; }
        __syncthreads();
        if (tid < 64) {
            float s = (sred[tid] + sred[64 + tid]) + (sred[128 + tid] + sred[192 + tid]);
            atomicAdd(&wsQ[(blockIdx.x & (NBANK - 1)) * 64 + tid], s);
        }
        const int cg = c0 + w * 32 + (l & 31);
        if (cg < C_DIM) {
            #pragma unroll
            for (int rr = 0; rr < 32; ++rr) {
                const int b = 2 * rr + hi;
                out[1 + (size_t)b * C_DIM + cg] = ldsT[b * 33 + (l & 31)];
            }
        }
    } else {
        // ================= h-loss block =================
        float* inv = shm;                      // [64]
        float* contrib = shm + 64;             // [64]
        const int r = tid >> 2, q = tid & 3;
        {
            const float* row = X + r * D_DIM + q * 64;
            float s = 0.0f;
            #pragma unroll
            for (int i = 0; i < 64; i += 4) {
                float4 v = *(const float4*)(row + i);
                s += v.x * v.x + v.y * v.y + v.z * v.z + v.w * v.w;
            }
            s += __shfl_xor(s, 1);
            s += __shfl_xor(s, 2);
            if (q == 0) inv[r] = 1.0f / fmaxf(sqrtf(s), 1e-12f);
        }
        __syncthreads();
        const float* Ar = X + r * D_DIM;
        const float ir = inv[r];
        const float INF = __int_as_float(0x7f800000);
        float m = INF;
        #pragma unroll
        for (int pp = 0; pp < 2; ++pp) {
            int p = q * 2 + pp;
            if (pos_mask[r * P_DIM + p]) {
                int j = pos_idx[r * P_DIM + p];
                float d = dot256(Ar, X + j * D_DIM) * ir * inv[j];
                m = fminf(m, d);
            }
        }
        m = fminf(m, __shfl_xor(m, 1));
        m = fminf(m, __shfl_xor(m, 2));
        const float thr = m - 0.3f;
        float sum = 0.0f; int cnt = 0;
        #pragma unroll 2
        for (int nn = 0; nn < 8; ++nn) {
            int n = q * 8 + nn;
            if (neg_mask[r * N_DIM + n]) {
                int j = neg_idx[r * N_DIM + n];
                float d = dot256(Ar, X + j * D_DIM) * ir * inv[j];
                if (d > thr) { cnt += 1; sum += softplusf(d); }
            }
        }
        sum += __shfl_xor(sum, 1); cnt += __shfl_xor(cnt, 1);
        sum += __shfl_xor(sum, 2); cnt += __shfl_xor(cnt, 2);
        if (q == 0) contrib[r] = softplusf(-m) + ((cnt > 0) ? sum / (float)cnt : 0.0f);
        __syncthreads();
        if (tid == 0) {
            float s = 0.0f;
            for (int i = 0; i < 64; ++i) s += contrib[i];
            wsH[0] = s * (1.0f / 64.0f);
        }
    }
}

// ---------------- Kernel C: finalize loss ----------------
__global__ __launch_bounds__(64)
void final_kernel(float* __restrict__ out, const float* __restrict__ wsQ,
                  const float* __restrict__ wsT, const float* __restrict__ wsH) {
    int b = threadIdx.x;
    float S = 0.0f;
    #pragma unroll
    for (int k = 0; k < NBANK; ++k) S += wsQ[k * 64 + b];
    float lb = logf(S) - wsT[b];
    #pragma unroll
    for (int m = 1; m <= 32; m <<= 1) lb += __shfl_xor(lb, m);
    if (b == 0) out[0] = lb * (1.0f / 64.0f) + wsH[0];
}

extern "C" void kernel_launch(void* const* d_in, const int* in_sizes, int n_in,
                              void* d_out, int out_size, void* d_ws, size_t ws_size,
                              hipStream_t stream) {
    (void)in_sizes; (void)n_in; (void)out_size; (void)ws_size;
    const float* X        = (const float*)d_in[0];
    const float* V        = (const float*)d_in[1];
    const int*   targets  = (const int*)d_in[2];
    const int*   pos_idx  = (const int*)d_in[3];
    const int*   pos_mask = (const int*)d_in[4];
    const int*   neg_idx  = (const int*)d_in[5];
    const int*   neg_mask = (const int*)d_in[6];
    float* out = (float*)d_out;
    float*          wsH = (float*)d_ws;                              // 64 floats
    float*          wsQ = (float*)d_ws + 64;                         // NBANK*64 = 4096
    float*          wsT = (float*)d_ws + 64 + NBANK * 64;            // 64
    unsigned short* wsA = (unsigned short*)((char*)d_ws + 32768);    // 32 KB A-fragments

    hipLaunchKernelGGL(frag_kernel, dim3(8), dim3(256), 0, stream, X, wsA, wsQ, wsT);
    hipLaunchKernelGGL(logits_kernel, dim3(GRID_TOT), dim3(256), 0, stream,
                       V, X, wsA, targets, pos_idx, pos_mask, neg_idx, neg_mask,
                       out, wsQ, wsT, wsH);
    hipLaunchKernelGGL(final_kernel, dim3(1), dim3(64), 0, stream, out, wsQ, wsT, wsH);
}

// Round 11
// 43.202 us; speedup vs baseline: 4.4239x; 2.0486x over previous
//
#include <hip/hip_runtime.h>
#include <hip/hip_bf16.h>
#include <math.h>

#define B_DIM 64
#define D_DIM 256
#define C_DIM 100000
#define P_DIM 8
#define N_DIM 32
#define BLK_COLS 64
#define GBLK 1563       // ceil(C_DIM / 64)
#define NCHUNK 8        // K chunks of 32
#define NBANK 64        // exp-sum accumulator banks

typedef __attribute__((ext_vector_type(8))) short bf16x8;
typedef __attribute__((ext_vector_type(16))) float f32x16;

__device__ __forceinline__ unsigned short bf16_rn(float f) {
    unsigned int u = __float_as_uint(f);
    unsigned int r = (u + 0x7FFFu + ((u >> 16) & 1u)) >> 16;
    return (unsigned short)r;
}

// Truncate-split: x = hi + lo (hi exact truncation, lo rounds; combined ~2^-17 rel err)
__device__ __forceinline__ void split_bf16(float x, unsigned short& hi, unsigned short& lo) {
    unsigned int bx = __float_as_uint(x);
    unsigned int hb = bx & 0xFFFF0000u;
    hi = (unsigned short)(hb >> 16);
    lo = bf16_rn(x - __uint_as_float(hb));
}

__device__ __forceinline__ float softplusf(float x) { return log1pf(expf(x)); }

__device__ __forceinline__ short f2bf(float x) {
    __hip_bfloat16 b = __float2bfloat16(x);   // pairs into v_cvt_pk_bf16_f32
    return *reinterpret_cast<short*>(&b);
}

// async 16B global->LDS copy; lds base is wave-uniform (HW adds lane*16)
__device__ __forceinline__ void async_copy16(const float* src, float* lds_base) {
    __builtin_amdgcn_global_load_lds(
        (const __attribute__((address_space(1))) unsigned int*)src,
        (__attribute__((address_space(3))) unsigned int*)lds_base,
        16, 0, 0);
}

// ---------------- Kernel A: norms, sim = ni@ni^T (hi+lo MFMA), hp/hn losses, A-frag precompute ----------------
// (R7's 512-thread prep, verified: sim/h-loss via MFMA — NOT fp32 gather-dots, which
// were a 40-50us straggler in R8-R10.)
__global__ __launch_bounds__(512)
void prep_kernel(const float* __restrict__ X,
                 const int* __restrict__ pos_idx, const int* __restrict__ pos_mask,
                 const int* __restrict__ neg_idx, const int* __restrict__ neg_mask,
                 float* __restrict__ wsH, unsigned short* __restrict__ wsA,
                 float* __restrict__ wsQ, float* __restrict__ wsT) {
    __shared__ unsigned short fHi[2048 * 8];   // 32 KB
    __shared__ unsigned short fLo[2048 * 8];   // 32 KB
    __shared__ float sim[64][64];              // 16 KB
    __shared__ float inv[64];
    __shared__ float hp[64];
    __shared__ float contrib[64];
    const int tid = threadIdx.x;
    for (int i = tid; i < NBANK * 64; i += 512) wsQ[i] = 0.0f;
    if (tid < 64) wsT[tid] = 0.0f;
    // row norms: 4 threads per row (first 4 waves)
    if (tid < 256) {
        int r = tid >> 2, q = tid & 3;
        const float* row = X + r * D_DIM + q * 64;
        float s = 0.0f;
        #pragma unroll
        for (int i = 0; i < 64; i += 4) {
            float4 v = *(const float4*)(row + i);
            s += v.x * v.x + v.y * v.y + v.z * v.z + v.w * v.w;
        }
        s += __shfl_xor(s, 1);
        s += __shfl_xor(s, 2);
        if (q == 0) inv[r] = 1.0f / fmaxf(sqrtf(s), 1e-12f);
    }
    __syncthreads();
    // fragments: lane l holds M[mt*32+(l&31)][kg*16+8*(l>>5)+j]
    for (int t = tid; t < 2048; t += 512) {
        int l = t & 63, kg = (t >> 6) & 15, mt = t >> 10;
        int row = mt * 32 + (l & 31);
        int col0 = kg * 16 + 8 * (l >> 5);
        const float* src = X + row * D_DIM + col0;
        float iv = inv[row];
        #pragma unroll
        for (int j = 0; j < 8; ++j) {
            unsigned short h, lo;
            split_bf16(src[j] * iv, h, lo);
            fHi[t * 8 + j] = h;
            fLo[t * 8 + j] = lo;
            wsA[t * 8 + j] = (unsigned short)f2bf(src[j]);
        }
    }
    __syncthreads();
    // sim via 4 wave tiles of 32x32 (waves 0-3)
    if ((tid >> 6) < 4) {
        int w = tid >> 6, l = tid & 63;
        int mt = w >> 1, nt = w & 1;
        f32x16 acc;
        #pragma unroll
        for (int i = 0; i < 16; ++i) acc[i] = 0.0f;
        #pragma unroll
        for (int ks = 0; ks < 16; ++ks) {
            const bf16x8 ah = *(const bf16x8*)&fHi[((mt * 16 + ks) * 64 + l) * 8];
            const bf16x8 al = *(const bf16x8*)&fLo[((mt * 16 + ks) * 64 + l) * 8];
            const bf16x8 bh = *(const bf16x8*)&fHi[((nt * 16 + ks) * 64 + l) * 8];
            const bf16x8 bl = *(const bf16x8*)&fLo[((nt * 16 + ks) * 64 + l) * 8];
            acc = __builtin_amdgcn_mfma_f32_32x32x16_bf16(ah, bh, acc, 0, 0, 0);
            acc = __builtin_amdgcn_mfma_f32_32x32x16_bf16(al, bh, acc, 0, 0, 0);
            acc = __builtin_amdgcn_mfma_f32_32x32x16_bf16(ah, bl, acc, 0, 0, 0);
        }
        #pragma unroll
        for (int r = 0; r < 16; ++r) {
            int brow = mt * 32 + (r & 3) + 8 * (r >> 2) + 4 * (l >> 5);
            int bcol = nt * 32 + (l & 31);
            sim[brow][bcol] = acc[r];
        }
    }
    __syncthreads();
    // hardest positive
    if (tid < 256) {
        int r = tid >> 2, q = tid & 3;
        const float INF = __int_as_float(0x7f800000);
        float m = INF;
        #pragma unroll
        for (int pp = 0; pp < 2; ++pp) {
            int p = q * 2 + pp;
            int j = pos_idx[r * P_DIM + p];
            int msk = pos_mask[r * P_DIM + p];
            float ps = sim[r][j];
            m = fminf(m, msk ? ps : INF);
        }
        m = fminf(m, __shfl_xor(m, 1));
        m = fminf(m, __shfl_xor(m, 2));
        if (q == 0) hp[r] = m;
    }
    __syncthreads();
    // hard negatives
    if (tid < 256) {
        int r = tid >> 2, q = tid & 3;
        float thr = hp[r] - 0.3f;
        float sum = 0.0f; int cnt = 0;
        #pragma unroll
        for (int nn = 0; nn < 8; ++nn) {
            int n = q * 8 + nn;
            int j = neg_idx[r * N_DIM + n];
            int msk = neg_mask[r * N_DIM + n];
            float ns = sim[r][j];
            if (msk && (ns > thr)) { cnt += 1; sum += softplusf(ns); }
        }
        sum += __shfl_xor(sum, 1); cnt += __shfl_xor(cnt, 1);
        sum += __shfl_xor(sum, 2); cnt += __shfl_xor(cnt, 2);
        if (q == 0) {
            float hn = (cnt > 0) ? (sum / (float)cnt) : 0.0f;
            contrib[r] = softplusf(-hp[r]) + hn;
        }
    }
    __syncthreads();
    if (tid == 0) {
        float s = 0.0f;
        for (int i = 0; i < 64; ++i) s += contrib[i];
        wsH[0] = s * (1.0f / 64.0f);
    }
}

// ---------------- Kernel B: logits^T = V_tile @ X^T, 64-col tiles, 2-wave blocks ----------------
// Same proven loop body as R6 (chunk K=32, dbuf async-LDS, plain __syncthreads, XOR
// swizzle on global source), but 64 cols / 128 thr => LDS ~17.5 KB => 9 blocks/CU
// (vs 4): more independent barrier groups per CU to cover the per-chunk drain stall.
__global__ __launch_bounds__(128)
void logits_kernel(const float* __restrict__ V, const unsigned short* __restrict__ wsA,
                   const int* __restrict__ targets, float* __restrict__ out,
                   float* __restrict__ wsQ, float* __restrict__ wsT) {
    __shared__ float shm[4352];                // stage 2x8 KB; epilogue 17 KB overlay
    __shared__ int tgt[64];
    const int tid = threadIdx.x;
    const int w = tid >> 6, l = tid & 63;      // w in {0,1}
    const int c0 = blockIdx.x * BLK_COLS;
    const int hi = l >> 5;
    if (tid < 64) tgt[tid] = targets[tid];

    // stage chunk kc (64 cols x 32 k = 8 KB) into buffer b; 16B units XOR-swizzled
    // (unit ^= col&7) applied on the GLOBAL source; gload_lds dest stays linear.
    #define STAGE(kc, b)                                                        \
        {                                                                       \
            _Pragma("unroll")                                                   \
            for (int j = 0; j < 4; ++j) {                                       \
                int U = (j * 2 + w) * 64 + l;                                   \
                int colL = U >> 3, up = U & 7;                                  \
                int us = up ^ (colL & 7);                                       \
                int cc = c0 + colL; cc = (cc < C_DIM) ? cc : (C_DIM - 1);       \
                const float* src = V + (size_t)cc * D_DIM + (kc) * 32 + us * 4; \
                async_copy16(src, &shm[(b) * 2048 + (j * 2 + w) * 256]);        \
            }                                                                   \
        }

    STAGE(0, 0);
    __syncthreads();

    f32x16 acc0, acc1;                         // batch rows 0-31, 32-63
    #pragma unroll
    for (int i = 0; i < 16; ++i) { acc0[i] = 0.0f; acc1[i] = 0.0f; }

    const int colL = w * 32 + (l & 31);
    const int cbase = colL * 32;               // 8 units * 4 floats per col
    const int cm7 = colL & 7;

    for (int kc = 0; kc < NCHUNK; ++kc) {
        if (kc < NCHUNK - 1) STAGE(kc + 1, (kc + 1) & 1);
        const float* vb = &shm[(kc & 1) * 2048];
        #pragma unroll
        for (int h = 0; h < 2; ++h) {
            const int kg = kc * 2 + h;
            const bf16x8 a0 = *(const bf16x8*)(wsA + ((0 * 16 + kg) * 64 + l) * 8);
            const bf16x8 a1 = *(const bf16x8*)(wsA + ((1 * 16 + kg) * 64 + l) * 8);
            const int u0 = h * 4 + 2 * hi;
            float4 v0 = *(const float4*)&vb[cbase + ((u0    ) ^ cm7) * 4];
            float4 v1 = *(const float4*)&vb[cbase + ((u0 + 1) ^ cm7) * 4];
            bf16x8 vh;
            vh[0] = f2bf(v0.x); vh[1] = f2bf(v0.y); vh[2] = f2bf(v0.z); vh[3] = f2bf(v0.w);
            vh[4] = f2bf(v1.x); vh[5] = f2bf(v1.y); vh[6] = f2bf(v1.z); vh[7] = f2bf(v1.w);
            // TRANSPOSED: A = V fragment, B = X fragment
            acc0 = __builtin_amdgcn_mfma_f32_32x32x16_bf16(vh, a0, acc0, 0, 0, 0);
            acc1 = __builtin_amdgcn_mfma_f32_32x32x16_bf16(vh, a1, acc1, 0, 0, 0);
        }
        __syncthreads();
    }
    #undef STAGE

    // ---- epilogue: lane-local exp-sums + target capture + LDS transpose ----
    float* ldsT = &shm[w * 2112];              // [64 b][33 c] per wave (2 waves)
    float* sred = &shm[4224];                  // [2 waves][64 b]
    const int b0 = l & 31, b1 = 32 + (l & 31);
    const int tb0 = tgt[b0], tb1 = tgt[b1];
    float s0 = 0.0f, s1 = 0.0f;
    #pragma unroll
    for (int r = 0; r < 16; ++r) {
        const int cl = (r & 3) + 8 * (r >> 2) + 4 * hi;
        const int c = c0 + w * 32 + cl;
        const float v0 = acc0[r], v1 = acc1[r];
        ldsT[b0 * 33 + cl] = v0;
        ldsT[b1 * 33 + cl] = v1;
        if (c < C_DIM) {
            s0 += expf(v0);
            s1 += expf(v1);
            if (c == tb0) atomicAdd(&wsT[b0], v0);
            if (c == tb1) atomicAdd(&wsT[b1], v1);
        }
    }
    s0 += __shfl_xor(s0, 32);                  // add the partner c-half
    s1 += __shfl_xor(s1, 32);
    if (l < 32) { sred[w * 64 + l] = s0; sred[w * 64 + 32 + l] = s1; }
    __syncthreads();
    if (tid < 64) {
        float s = sred[tid] + sred[64 + tid];
        atomicAdd(&wsQ[(blockIdx.x & (NBANK - 1)) * 64 + tid], s);
    }
    // store this wave's 32 columns (contiguous 128B segments per instruction)
    const int cg = c0 + w * 32 + (l & 31);
    if (cg < C_DIM) {
        #pragma unroll
        for (int rr = 0; rr < 32; ++rr) {
            const int b = 2 * rr + hi;
            out[1 + (size_t)b * C_DIM + cg] = ldsT[b * 33 + (l & 31)];
        }
    }
}

// ---------------- Kernel C: finalize loss ----------------
__global__ __launch_bounds__(64)
void final_kernel(float* __restrict__ out, const float* __restrict__ wsQ,
                  const float* __restrict__ wsT, const float* __restrict__ wsH) {
    int b = threadIdx.x;
    float S = 0.0f;
    #pragma unroll
    for (int k = 0; k < NBANK; ++k) S += wsQ[k * 64 + b];
    float lb = logf(S) - wsT[b];
    #pragma unroll
    for (int m = 1; m <= 32; m <<= 1) lb += __shfl_xor(lb, m);
    if (b == 0) out[0] = lb * (1.0f / 64.0f) + wsH[0];
}

extern "C" void kernel_launch(void* const* d_in, const int* in_sizes, int n_in,
                              void* d_out, int out_size, void* d_ws, size_t ws_size,
                              hipStream_t stream) {
    (void)in_sizes; (void)n_in; (void)out_size; (void)ws_size;
    const float* X        = (const float*)d_in[0];
    const float* V        = (const float*)d_in[1];
    const int*   targets  = (const int*)d_in[2];
    const int*   pos_idx  = (const int*)d_in[3];
    const int*   pos_mask = (const int*)d_in[4];
    const int*   neg_idx  = (const int*)d_in[5];
    const int*   neg_mask = (const int*)d_in[6];
    float* out = (float*)d_out;
    float*          wsH = (float*)d_ws;                              // 64 floats
    float*          wsQ = (float*)d_ws + 64;                         // NBANK*64 = 4096
    float*          wsT = (float*)d_ws + 64 + NBANK * 64;            // 64
    unsigned short* wsA = (unsigned short*)((char*)d_ws + 32768);    // 32 KB A-fragments

    hipLaunchKernelGGL(prep_kernel, dim3(1), dim3(512), 0, stream,
                       X, pos_idx, pos_mask, neg_idx, neg_mask, wsH, wsA, wsQ, wsT);
    hipLaunchKernelGGL(logits_kernel, dim3(GBLK), dim3(128), 0, stream,
                       V, wsA, targets, out, wsQ, wsT);
    hipLaunchKernelGGL(final_kernel, dim3(1), dim3(64), 0, stream, out, wsQ, wsT, wsH);
}